// Round 1
// baseline (220.645 us; speedup 1.0000x reference)
//
#include <hip/hip_runtime.h>
#include <hip/hip_bf16.h>

#define H 8
#define DMODEL 512
#define DK 64
#define BATCH 4
#define SEQ 2048
#define M_TOTAL (BATCH*SEQ)

typedef short bf16x8 __attribute__((ext_vector_type(8)));
typedef float f32x4 __attribute__((ext_vector_type(4)));

__device__ __forceinline__ unsigned short f2bf(float f) {
    unsigned int u = __builtin_bit_cast(unsigned int, f);
    u += 0x7FFFu + ((u >> 16) & 1u);
    return (unsigned short)(u >> 16);
}

// ---------------------------------------------------------------------------
// NT GEMM: C[m][n] = sum_k A[m][k] * B[n][k] + bias[n]
// A: fp32 (modes 0-2) or bf16 (mode 3), M=8192 x K=512, row-major
// B: fp32 weights, N=512 x K=512, row-major (einsum 'bsd,ed->bse' => W[e][d])
// MODE 0: Q proj -> bf16 (b,h,s,dk), scaled by 1/8
// MODE 1: K proj -> bf16 (b,h,s,dk)
// MODE 2: V proj -> bf16 (b,h,dk,s)  (pre-transposed for PV MFMA)
// MODE 3: O proj -> fp32 (b,s,e) = d_out
// ---------------------------------------------------------------------------
template<int MODE>
__global__ __launch_bounds__(256) void gemm_proj(
    const void* __restrict__ Av, const float* __restrict__ Bw,
    const float* __restrict__ bias, void* __restrict__ out)
{
    const int m0 = blockIdx.x * 128;
    const int n0 = blockIdx.y * 128;
    const int tid = threadIdx.x;
    const int lane = tid & 63;
    const int w = tid >> 6;
    const int wm = w >> 1, wn = w & 1;

    __shared__ unsigned short Alds[128 * 40];  // stride 40 elems = 80B (16B aligned, 2-way banks)
    __shared__ unsigned short Blds[128 * 40];

    f32x4 acc[4][4];
    #pragma unroll
    for (int i = 0; i < 4; i++)
        #pragma unroll
        for (int j = 0; j < 4; j++)
            acc[i][j] = f32x4{0.f, 0.f, 0.f, 0.f};

    for (int k0 = 0; k0 < 512; k0 += 32) {
        // ---- stage A tile 128x32 ----
        if constexpr (MODE == 3) {
            const unsigned short* A = (const unsigned short*)Av;
            #pragma unroll
            for (int i = 0; i < 2; i++) {
                int idx = tid + i * 256;
                int row = idx >> 2, c = idx & 3;          // 4 chunks of 8 bf16
                bf16x8 v = *(const bf16x8*)(A + (size_t)(m0 + row) * 512 + k0 + c * 8);
                *(bf16x8*)(Alds + row * 40 + c * 8) = v;
            }
        } else {
            const float* A = (const float*)Av;
            #pragma unroll
            for (int i = 0; i < 4; i++) {
                int idx = tid + i * 256;
                int row = idx >> 3, c = idx & 7;          // 8 chunks of 4 fp32
                float4 v = *(const float4*)(A + (size_t)(m0 + row) * 512 + k0 + c * 4);
                ushort4 bv;
                bv.x = f2bf(v.x); bv.y = f2bf(v.y); bv.z = f2bf(v.z); bv.w = f2bf(v.w);
                *(ushort4*)(Alds + row * 40 + c * 4) = bv;
            }
        }
        // ---- stage B tile 128x32 (fp32 weights -> bf16) ----
        {
            #pragma unroll
            for (int i = 0; i < 4; i++) {
                int idx = tid + i * 256;
                int row = idx >> 3, c = idx & 7;
                float4 v = *(const float4*)(Bw + (size_t)(n0 + row) * 512 + k0 + c * 4);
                ushort4 bv;
                bv.x = f2bf(v.x); bv.y = f2bf(v.y); bv.z = f2bf(v.z); bv.w = f2bf(v.w);
                *(ushort4*)(Blds + row * 40 + c * 4) = bv;
            }
        }
        __syncthreads();

        bf16x8 af[4], bfr[4];
        #pragma unroll
        for (int mt = 0; mt < 4; mt++)
            af[mt] = *(const bf16x8*)(Alds + (wm * 64 + mt * 16 + (lane & 15)) * 40 + (lane >> 4) * 8);
        #pragma unroll
        for (int nt = 0; nt < 4; nt++)
            bfr[nt] = *(const bf16x8*)(Blds + (wn * 64 + nt * 16 + (lane & 15)) * 40 + (lane >> 4) * 8);
        #pragma unroll
        for (int mt = 0; mt < 4; mt++)
            #pragma unroll
            for (int nt = 0; nt < 4; nt++)
                acc[mt][nt] = __builtin_amdgcn_mfma_f32_16x16x32_bf16(af[mt], bfr[nt], acc[mt][nt], 0, 0, 0);
        __syncthreads();
    }

    // ---- epilogue ----
    #pragma unroll
    for (int mt = 0; mt < 4; mt++) {
        int mbase = m0 + wm * 64 + mt * 16 + ((lane >> 4) << 2);
        #pragma unroll
        for (int nt = 0; nt < 4; nt++) {
            int n = n0 + wn * 64 + nt * 16 + (lane & 15);
            float bv = bias[n];
            if constexpr (MODE == 0 || MODE == 1) {
                unsigned short* O = (unsigned short*)out;
                int h = n >> 6, dk = n & 63;
                #pragma unroll
                for (int r = 0; r < 4; r++) {
                    int m = mbase + r;
                    int b = m >> 11, s = m & 2047;
                    float v = acc[mt][nt][r] + bv;
                    if (MODE == 0) v *= 0.125f;   // fold 1/sqrt(64)
                    O[((size_t)(b * H + h) * SEQ + s) * 64 + dk] = f2bf(v);
                }
            } else if constexpr (MODE == 2) {
                unsigned short* O = (unsigned short*)out;
                int h = n >> 6, dk = n & 63;
                int b = mbase >> 11, s = mbase & 2047;   // 4 rows same b (128-aligned tiles)
                ushort4 pk;
                pk.x = f2bf(acc[mt][nt][0] + bv);
                pk.y = f2bf(acc[mt][nt][1] + bv);
                pk.z = f2bf(acc[mt][nt][2] + bv);
                pk.w = f2bf(acc[mt][nt][3] + bv);
                *(ushort4*)(O + ((size_t)(b * H + h) * 64 + dk) * SEQ + s) = pk;
            } else {
                float* O = (float*)out;
                #pragma unroll
                for (int r = 0; r < 4; r++) {
                    int m = mbase + r;
                    O[(size_t)m * 512 + n] = acc[mt][nt][r] + bv;
                }
            }
        }
    }
}

// ---------------------------------------------------------------------------
// Flash attention: grid (S/64, B*H), 256 threads = 4 waves x 16 q-rows.
// Q pre-scaled by 1/8. K: (b,h,s,dk) bf16. Vt: (b,h,dk,s) bf16.
// Output Xattn: (b,s,h*64+dk) bf16.
// ---------------------------------------------------------------------------
__global__ __launch_bounds__(256) void attn_kernel(
    const unsigned short* __restrict__ Qh,
    const unsigned short* __restrict__ Kh,
    const unsigned short* __restrict__ Vt,
    const int* __restrict__ mask,
    unsigned short* __restrict__ Xattn)
{
    const int tid = threadIdx.x;
    const int lane = tid & 63;
    const int w = tid >> 6;
    const int q0 = blockIdx.x * 64;
    const int bh = blockIdx.y;
    const int b = bh >> 3;

    __shared__ unsigned short Klds[64 * 72];   // stride 72 elems = 144B (16B aligned)
    __shared__ unsigned short Vlds[64 * 72];
    __shared__ unsigned short Plds[4][16 * 72];

    // Q fragments (held in registers for entire kernel): A-layout m=lane&15, k=(lane>>4)*8+j
    bf16x8 qf[2];
    {
        const unsigned short* Qbase =
            Qh + ((size_t)bh * SEQ + q0 + w * 16 + (lane & 15)) * 64 + (lane >> 4) * 8;
        qf[0] = *(const bf16x8*)(Qbase);
        qf[1] = *(const bf16x8*)(Qbase + 32);
    }

    f32x4 acc_o[4];
    #pragma unroll
    for (int dt = 0; dt < 4; dt++) acc_o[dt] = f32x4{0.f, 0.f, 0.f, 0.f};
    float m_run[4], l_run[4];
    #pragma unroll
    for (int r = 0; r < 4; r++) { m_run[r] = -1e30f; l_run[r] = 0.f; }

    const unsigned short* Kbh = Kh + (size_t)bh * SEQ * 64;
    const unsigned short* Vbh = Vt + (size_t)bh * 64 * SEQ;
    const int* maskb = mask + b * SEQ;

    for (int kv0 = 0; kv0 < SEQ; kv0 += 64) {
        // ---- stage K (64x64) and V^T (64x64) tiles ----
        #pragma unroll
        for (int i = 0; i < 2; i++) {
            int idx = tid + i * 256;
            int row = idx >> 3, c = idx & 7;
            *(bf16x8*)(Klds + row * 72 + c * 8) =
                *(const bf16x8*)(Kbh + (size_t)(kv0 + row) * 64 + c * 8);
        }
        #pragma unroll
        for (int i = 0; i < 2; i++) {
            int idx = tid + i * 256;
            int row = idx >> 3, c = idx & 7;
            *(bf16x8*)(Vlds + row * 72 + c * 8) =
                *(const bf16x8*)(Vbh + (size_t)row * SEQ + kv0 + c * 8);
        }
        __syncthreads();

        // ---- S = Q K^T (rows = q, cols = kv) ----
        f32x4 sacc[4];
        #pragma unroll
        for (int nt = 0; nt < 4; nt++) {
            const unsigned short* kb = Klds + (nt * 16 + (lane & 15)) * 72 + (lane >> 4) * 8;
            bf16x8 kf0 = *(const bf16x8*)(kb);
            bf16x8 kf1 = *(const bf16x8*)(kb + 32);
            f32x4 sa = f32x4{0.f, 0.f, 0.f, 0.f};
            sa = __builtin_amdgcn_mfma_f32_16x16x32_bf16(qf[0], kf0, sa, 0, 0, 0);
            sa = __builtin_amdgcn_mfma_f32_16x16x32_bf16(qf[1], kf1, sa, 0, 0, 0);
            sacc[nt] = sa;
        }

        // ---- mask (key-wise) ----
        #pragma unroll
        for (int nt = 0; nt < 4; nt++) {
            if (maskb[kv0 + nt * 16 + (lane & 15)] == 0) {
                #pragma unroll
                for (int r = 0; r < 4; r++) sacc[nt][r] = -1e9f;
            }
        }

        // ---- online softmax (wave-parallel: rows live on 16-lane groups) ----
        #pragma unroll
        for (int r = 0; r < 4; r++) {
            float rmax = fmaxf(fmaxf(sacc[0][r], sacc[1][r]), fmaxf(sacc[2][r], sacc[3][r]));
            rmax = fmaxf(rmax, __shfl_xor(rmax, 1));
            rmax = fmaxf(rmax, __shfl_xor(rmax, 2));
            rmax = fmaxf(rmax, __shfl_xor(rmax, 4));
            rmax = fmaxf(rmax, __shfl_xor(rmax, 8));
            float mnew = fmaxf(m_run[r], rmax);
            float alpha = exp2f((m_run[r] - mnew) * 1.44269504f);
            float ps = 0.f;
            #pragma unroll
            for (int nt = 0; nt < 4; nt++) {
                float p = exp2f((sacc[nt][r] - mnew) * 1.44269504f);
                ps += p;
                Plds[w][((lane >> 4) * 4 + r) * 72 + nt * 16 + (lane & 15)] = f2bf(p);
            }
            ps += __shfl_xor(ps, 1);
            ps += __shfl_xor(ps, 2);
            ps += __shfl_xor(ps, 4);
            ps += __shfl_xor(ps, 8);
            l_run[r] = l_run[r] * alpha + ps;
            m_run[r] = mnew;
            #pragma unroll
            for (int dt = 0; dt < 4; dt++) acc_o[dt][r] *= alpha;
        }

        // ---- O += P V  (A = P via LDS transpose, B = V^T tile) ----
        bf16x8 pf0 = *(const bf16x8*)(&Plds[w][(lane & 15) * 72 + (lane >> 4) * 8]);
        bf16x8 pf1 = *(const bf16x8*)(&Plds[w][(lane & 15) * 72 + 32 + (lane >> 4) * 8]);
        #pragma unroll
        for (int dt = 0; dt < 4; dt++) {
            const unsigned short* vb = Vlds + (dt * 16 + (lane & 15)) * 72 + (lane >> 4) * 8;
            bf16x8 vf0 = *(const bf16x8*)(vb);
            bf16x8 vf1 = *(const bf16x8*)(vb + 32);
            acc_o[dt] = __builtin_amdgcn_mfma_f32_16x16x32_bf16(pf0, vf0, acc_o[dt], 0, 0, 0);
            acc_o[dt] = __builtin_amdgcn_mfma_f32_16x16x32_bf16(pf1, vf1, acc_o[dt], 0, 0, 0);
        }
        __syncthreads();
    }

    // ---- epilogue: normalize and write (b, s, h*64+d) bf16 ----
    const int h = bh & 7;
    const int qrow_base = q0 + w * 16 + ((lane >> 4) << 2);
    #pragma unroll
    for (int r = 0; r < 4; r++) {
        float inv = 1.0f / l_run[r];
        int s = qrow_base + r;
        size_t base = ((size_t)b * SEQ + s) * 512 + h * 64;
        #pragma unroll
        for (int dt = 0; dt < 4; dt++) {
            Xattn[base + dt * 16 + (lane & 15)] = f2bf(acc_o[dt][r] * inv);
        }
    }
}

extern "C" void kernel_launch(void* const* d_in, const int* in_sizes, int n_in,
                              void* d_out, int out_size, void* d_ws, size_t ws_size,
                              hipStream_t stream)
{
    const float* query = (const float*)d_in[0];
    const float* key_  = (const float*)d_in[1];
    const float* value = (const float*)d_in[2];
    const int*   mask  = (const int*)d_in[3];
    const float* Wq = (const float*)d_in[4];
    const float* bq = (const float*)d_in[5];
    const float* Wk = (const float*)d_in[6];
    const float* bk = (const float*)d_in[7];
    const float* Wv = (const float*)d_in[8];
    const float* bv = (const float*)d_in[9];
    const float* Wo = (const float*)d_in[10];
    const float* bo = (const float*)d_in[11];

    // workspace: 4 x 8MB bf16 buffers = 32 MB
    unsigned short* Qh = (unsigned short*)d_ws;                 // (b,h,s,dk), pre-scaled
    unsigned short* Kh = Qh + (size_t)M_TOTAL * DMODEL;         // (b,h,s,dk)
    unsigned short* Vt = Kh + (size_t)M_TOTAL * DMODEL;         // (b,h,dk,s)
    unsigned short* Xa = Vt + (size_t)M_TOTAL * DMODEL;         // (b,s,e)

    dim3 gblk(64, 4), thr(256);
    hipLaunchKernelGGL((gemm_proj<0>), gblk, thr, 0, stream, (const void*)query, Wq, bq, (void*)Qh);
    hipLaunchKernelGGL((gemm_proj<1>), gblk, thr, 0, stream, (const void*)key_,  Wk, bk, (void*)Kh);
    hipLaunchKernelGGL((gemm_proj<2>), gblk, thr, 0, stream, (const void*)value, Wv, bv, (void*)Vt);
    hipLaunchKernelGGL(attn_kernel, dim3(SEQ / 64, BATCH * H), thr, 0, stream, Qh, Kh, Vt, mask, Xa);
    hipLaunchKernelGGL((gemm_proj<3>), gblk, thr, 0, stream, (const void*)Xa, Wo, bo, d_out);
}

// Round 2
// 178.962 us; speedup vs baseline: 1.2329x; 1.2329x over previous
//
#include <hip/hip_runtime.h>
#include <hip/hip_bf16.h>

#define H 8
#define DMODEL 512
#define DK 64
#define BATCH 4
#define SEQ 2048
#define M_TOTAL (BATCH*SEQ)

typedef short bf16x8 __attribute__((ext_vector_type(8)));
typedef float f32x4 __attribute__((ext_vector_type(4)));

__device__ __forceinline__ unsigned short f2bf(float f) {
    unsigned int u = __builtin_bit_cast(unsigned int, f);
    u += 0x7FFFu + ((u >> 16) & 1u);
    return (unsigned short)(u >> 16);
}

// packed f32x2 -> bf16x2 (RTNE), one VALU op
__device__ __forceinline__ unsigned int pack_bf2(float a, float b) {
    unsigned int r;
    asm("v_cvt_pk_bf16_f32 %0, %1, %2" : "=v"(r) : "v"(a), "v"(b));
    return r;
}

// ---------------------------------------------------------------------------
// NT GEMM: C[m][n] = sum_k A[m][k] * B[n][k] + bias[n]
// MODE 0: Q proj -> bf16 (b,h,s,dk), scaled by 0.125*log2(e)
// MODE 1: K proj -> bf16 (b,h,s,dk)
// MODE 2: V proj -> bf16 (b,h,dk,s)  (pre-transposed for PV MFMA)
// MODE 3: O proj -> fp32 (b,s,e) = d_out
// ---------------------------------------------------------------------------
template<int MODE>
__global__ __launch_bounds__(256) void gemm_proj(
    const void* __restrict__ Av, const float* __restrict__ Bw,
    const float* __restrict__ bias, void* __restrict__ out)
{
    const int m0 = blockIdx.x * 128;
    const int n0 = blockIdx.y * 128;
    const int tid = threadIdx.x;
    const int lane = tid & 63;
    const int w = tid >> 6;
    const int wm = w >> 1, wn = w & 1;

    __shared__ unsigned short Alds[128 * 40];
    __shared__ unsigned short Blds[128 * 40];

    f32x4 acc[4][4];
    #pragma unroll
    for (int i = 0; i < 4; i++)
        #pragma unroll
        for (int j = 0; j < 4; j++)
            acc[i][j] = f32x4{0.f, 0.f, 0.f, 0.f};

    for (int k0 = 0; k0 < 512; k0 += 32) {
        if constexpr (MODE == 3) {
            const unsigned short* A = (const unsigned short*)Av;
            #pragma unroll
            for (int i = 0; i < 2; i++) {
                int idx = tid + i * 256;
                int row = idx >> 2, c = idx & 3;
                bf16x8 v = *(const bf16x8*)(A + (size_t)(m0 + row) * 512 + k0 + c * 8);
                *(bf16x8*)(Alds + row * 40 + c * 8) = v;
            }
        } else {
            const float* A = (const float*)Av;
            #pragma unroll
            for (int i = 0; i < 4; i++) {
                int idx = tid + i * 256;
                int row = idx >> 3, c = idx & 7;
                float4 v = *(const float4*)(A + (size_t)(m0 + row) * 512 + k0 + c * 4);
                ushort4 bv;
                bv.x = f2bf(v.x); bv.y = f2bf(v.y); bv.z = f2bf(v.z); bv.w = f2bf(v.w);
                *(ushort4*)(Alds + row * 40 + c * 4) = bv;
            }
        }
        {
            #pragma unroll
            for (int i = 0; i < 4; i++) {
                int idx = tid + i * 256;
                int row = idx >> 3, c = idx & 7;
                float4 v = *(const float4*)(Bw + (size_t)(n0 + row) * 512 + k0 + c * 4);
                ushort4 bv;
                bv.x = f2bf(v.x); bv.y = f2bf(v.y); bv.z = f2bf(v.z); bv.w = f2bf(v.w);
                *(ushort4*)(Blds + row * 40 + c * 4) = bv;
            }
        }
        __syncthreads();

        bf16x8 af[4], bfr[4];
        #pragma unroll
        for (int mt = 0; mt < 4; mt++)
            af[mt] = *(const bf16x8*)(Alds + (wm * 64 + mt * 16 + (lane & 15)) * 40 + (lane >> 4) * 8);
        #pragma unroll
        for (int nt = 0; nt < 4; nt++)
            bfr[nt] = *(const bf16x8*)(Blds + (wn * 64 + nt * 16 + (lane & 15)) * 40 + (lane >> 4) * 8);
        #pragma unroll
        for (int mt = 0; mt < 4; mt++)
            #pragma unroll
            for (int nt = 0; nt < 4; nt++)
                acc[mt][nt] = __builtin_amdgcn_mfma_f32_16x16x32_bf16(af[mt], bfr[nt], acc[mt][nt], 0, 0, 0);
        __syncthreads();
    }

    #pragma unroll
    for (int mt = 0; mt < 4; mt++) {
        int mbase = m0 + wm * 64 + mt * 16 + ((lane >> 4) << 2);
        #pragma unroll
        for (int nt = 0; nt < 4; nt++) {
            int n = n0 + wn * 64 + nt * 16 + (lane & 15);
            float bv = bias[n];
            if constexpr (MODE == 0 || MODE == 1) {
                unsigned short* O = (unsigned short*)out;
                int h = n >> 6, dk = n & 63;
                #pragma unroll
                for (int r = 0; r < 4; r++) {
                    int m = mbase + r;
                    int b = m >> 11, s = m & 2047;
                    float v = acc[mt][nt][r] + bv;
                    if (MODE == 0) v *= 0.18033688011112042f;   // (1/8)*log2(e)
                    O[((size_t)(b * H + h) * SEQ + s) * 64 + dk] = f2bf(v);
                }
            } else if constexpr (MODE == 2) {
                unsigned short* O = (unsigned short*)out;
                int h = n >> 6, dk = n & 63;
                int b = mbase >> 11, s = mbase & 2047;
                ushort4 pk;
                pk.x = f2bf(acc[mt][nt][0] + bv);
                pk.y = f2bf(acc[mt][nt][1] + bv);
                pk.z = f2bf(acc[mt][nt][2] + bv);
                pk.w = f2bf(acc[mt][nt][3] + bv);
                *(ushort4*)(O + ((size_t)(b * H + h) * 64 + dk) * SEQ + s) = pk;
            } else {
                float* O = (float*)out;
                #pragma unroll
                for (int r = 0; r < 4; r++) {
                    int m = mbase + r;
                    O[(size_t)m * 512 + n] = acc[mt][nt][r] + bv;
                }
            }
        }
    }
}

// ---------------------------------------------------------------------------
// Flash attention, swapped-QK^T variant.
// grid (S/64, B*H), 256 threads = 4 waves x 16 q-rows. KVBLK = 128.
// Q pre-scaled by 0.125*log2(e) (softmax computed in exp2 domain).
// S^T = mfma(K, Q): lane (g=lane>>4, qi=lane&15) holds S[kv=nt*16+4g+r][q=qi]
//   -> softmax row state (m_run, l_run) is PER-LANE scalar; row reduce is
//      in-register tree + 2 shuffles (xor 16, 32).
// P packed to bf16 via v_cvt_pk_bf16_f32, written b64 to per-wave Plds[q][kv],
// read back as PV B-fragment (contiguous b128).
// O^T = mfma(V^T, P^T): acc_o[dt] holds O[d=dt*16+4g+r][q=qi].
// ---------------------------------------------------------------------------
__global__ __launch_bounds__(256) void attn_kernel(
    const unsigned short* __restrict__ Qh,
    const unsigned short* __restrict__ Kh,
    const unsigned short* __restrict__ Vt,
    const int* __restrict__ mask,
    unsigned short* __restrict__ Xattn)
{
    const int tid = threadIdx.x;
    const int lane = tid & 63;
    const int w = tid >> 6;
    const int g = lane >> 4;
    const int qi = lane & 15;
    const int q0 = blockIdx.x * 64;
    const int bh = blockIdx.y;
    const int b = bh >> 3;

    __shared__ unsigned short Klds[128 * 72];     // [kv][d], stride 144B
    __shared__ unsigned short Vlds[64 * 136];     // [d][kv], stride 272B
    __shared__ unsigned short Plds[4][16 * 136];  // per-wave [q][kv]

    // Q B-fragment: B[n=qi][k=g*8+j], k-halves 0 / 32
    bf16x8 qf[2];
    {
        const unsigned short* Qbase = Qh + ((size_t)bh * SEQ + q0 + w * 16 + qi) * 64 + g * 8;
        qf[0] = *(const bf16x8*)(Qbase);
        qf[1] = *(const bf16x8*)(Qbase + 32);
    }

    f32x4 acc_o[4];
    #pragma unroll
    for (int dt = 0; dt < 4; dt++) acc_o[dt] = f32x4{0.f, 0.f, 0.f, 0.f};
    float m_run = -1e30f, l_run = 0.f;

    const unsigned short* Kbh = Kh + (size_t)bh * SEQ * 64;
    const unsigned short* Vbh = Vt + (size_t)bh * 64 * SEQ;
    const int* maskb = mask + b * SEQ;

    for (int kv0 = 0; kv0 < SEQ; kv0 += 128) {
        // ---- stage K (128x64) ----
        #pragma unroll
        for (int i = 0; i < 4; i++) {
            int idx = tid + i * 256;
            int row = idx >> 3, c = idx & 7;
            *(bf16x8*)(Klds + row * 72 + c * 8) =
                *(const bf16x8*)(Kbh + (size_t)(kv0 + row) * 64 + c * 8);
        }
        // ---- stage V^T (64x128) ----
        #pragma unroll
        for (int i = 0; i < 4; i++) {
            int idx = tid + i * 256;
            int row = idx >> 4, c = idx & 15;
            *(bf16x8*)(Vlds + row * 136 + c * 8) =
                *(const bf16x8*)(Vbh + (size_t)row * SEQ + kv0 + c * 8);
        }
        unsigned long long mb0 = __ballot(maskb[kv0 + lane] != 0);
        unsigned long long mb1 = __ballot(maskb[kv0 + 64 + lane] != 0);
        __syncthreads();

        // ---- S^T = K Q^T ----
        f32x4 sacc[8];
        #pragma unroll
        for (int nt = 0; nt < 8; nt++) {
            const unsigned short* kb = Klds + (nt * 16 + qi) * 72 + g * 8;
            bf16x8 kf0 = *(const bf16x8*)(kb);
            bf16x8 kf1 = *(const bf16x8*)(kb + 32);
            f32x4 sa = f32x4{0.f, 0.f, 0.f, 0.f};
            sa = __builtin_amdgcn_mfma_f32_16x16x32_bf16(kf0, qf[0], sa, 0, 0, 0);
            sa = __builtin_amdgcn_mfma_f32_16x16x32_bf16(kf1, qf[1], sa, 0, 0, 0);
            sacc[nt] = sa;
        }

        // ---- mask (rare path; bench mask is all-ones) ----
        if ((mb0 & mb1) != ~0ull) {
            #pragma unroll
            for (int nt = 0; nt < 8; nt++) {
                #pragma unroll
                for (int r = 0; r < 4; r++) {
                    int kvl = nt * 16 + g * 4 + r;
                    unsigned long long sel = (kvl < 64) ? mb0 : mb1;
                    if (!((sel >> (kvl & 63)) & 1ull)) sacc[nt][r] = -1e9f;
                }
            }
        }

        // ---- row max: in-lane tree + 2 shuffles ----
        float rmax;
        {
            float t[8];
            #pragma unroll
            for (int nt = 0; nt < 8; nt++)
                t[nt] = fmaxf(fmaxf(sacc[nt][0], sacc[nt][1]), fmaxf(sacc[nt][2], sacc[nt][3]));
            float a = fmaxf(fmaxf(t[0], t[1]), fmaxf(t[2], t[3]));
            float c = fmaxf(fmaxf(t[4], t[5]), fmaxf(t[6], t[7]));
            rmax = fmaxf(a, c);
        }
        rmax = fmaxf(rmax, __shfl_xor(rmax, 16));
        rmax = fmaxf(rmax, __shfl_xor(rmax, 32));

        // ---- defer-max rescale (THR = 8 in log2 units => P <= 256) ----
        if (__any(rmax > m_run + 8.0f)) {
            float mnew = fmaxf(m_run, rmax);
            float alpha = exp2f(m_run - mnew);
            #pragma unroll
            for (int dt = 0; dt < 4; dt++)
                #pragma unroll
                for (int r = 0; r < 4; r++) acc_o[dt][r] *= alpha;
            l_run *= alpha;
            m_run = mnew;
        }

        // ---- P = exp2(S - m), packed bf16, b64 writes ----
        float ps0 = 0.f, ps1 = 0.f;
        #pragma unroll
        for (int nt = 0; nt < 8; nt++) {
            float p0 = exp2f(sacc[nt][0] - m_run);
            float p1 = exp2f(sacc[nt][1] - m_run);
            float p2 = exp2f(sacc[nt][2] - m_run);
            float p3 = exp2f(sacc[nt][3] - m_run);
            ps0 += p0 + p1;
            ps1 += p2 + p3;
            uint2 pk;
            pk.x = pack_bf2(p0, p1);
            pk.y = pack_bf2(p2, p3);
            *(uint2*)(&Plds[w][qi * 136 + nt * 16 + g * 4]) = pk;
        }
        float ps = ps0 + ps1;
        ps += __shfl_xor(ps, 16);
        ps += __shfl_xor(ps, 32);
        l_run += ps;

        // ---- O^T += V^T P^T ----
        #pragma unroll
        for (int kt = 0; kt < 4; kt++) {
            bf16x8 pf = *(const bf16x8*)(&Plds[w][qi * 136 + kt * 32 + g * 8]);
            #pragma unroll
            for (int dt = 0; dt < 4; dt++) {
                bf16x8 vf = *(const bf16x8*)(Vlds + (dt * 16 + qi) * 136 + kt * 32 + g * 8);
                acc_o[dt] = __builtin_amdgcn_mfma_f32_16x16x32_bf16(vf, pf, acc_o[dt], 0, 0, 0);
            }
        }
        __syncthreads();
    }

    // ---- epilogue: normalize, write (b, s, h*64+d) ----
    const int h = bh & 7;
    const int s = q0 + w * 16 + qi;
    const float inv = 1.0f / l_run;
    size_t base = ((size_t)b * SEQ + s) * 512 + h * 64;
    #pragma unroll
    for (int dt = 0; dt < 4; dt++) {
        uint2 o;
        o.x = pack_bf2(acc_o[dt][0] * inv, acc_o[dt][1] * inv);
        o.y = pack_bf2(acc_o[dt][2] * inv, acc_o[dt][3] * inv);
        *(uint2*)(Xattn + base + dt * 16 + g * 4) = o;
    }
}

extern "C" void kernel_launch(void* const* d_in, const int* in_sizes, int n_in,
                              void* d_out, int out_size, void* d_ws, size_t ws_size,
                              hipStream_t stream)
{
    const float* query = (const float*)d_in[0];
    const float* key_  = (const float*)d_in[1];
    const float* value = (const float*)d_in[2];
    const int*   mask  = (const int*)d_in[3];
    const float* Wq = (const float*)d_in[4];
    const float* bq = (const float*)d_in[5];
    const float* Wk = (const float*)d_in[6];
    const float* bk = (const float*)d_in[7];
    const float* Wv = (const float*)d_in[8];
    const float* bv = (const float*)d_in[9];
    const float* Wo = (const float*)d_in[10];
    const float* bo = (const float*)d_in[11];

    unsigned short* Qh = (unsigned short*)d_ws;
    unsigned short* Kh = Qh + (size_t)M_TOTAL * DMODEL;
    unsigned short* Vt = Kh + (size_t)M_TOTAL * DMODEL;
    unsigned short* Xa = Vt + (size_t)M_TOTAL * DMODEL;

    dim3 gblk(64, 4), thr(256);
    hipLaunchKernelGGL((gemm_proj<0>), gblk, thr, 0, stream, (const void*)query, Wq, bq, (void*)Qh);
    hipLaunchKernelGGL((gemm_proj<1>), gblk, thr, 0, stream, (const void*)key_,  Wk, bk, (void*)Kh);
    hipLaunchKernelGGL((gemm_proj<2>), gblk, thr, 0, stream, (const void*)value, Wv, bv, (void*)Vt);
    hipLaunchKernelGGL(attn_kernel, dim3(SEQ / 64, BATCH * H), thr, 0, stream, Qh, Kh, Vt, mask, Xa);
    hipLaunchKernelGGL((gemm_proj<3>), gblk, thr, 0, stream, (const void*)Xa, Wo, bo, d_out);
}